// Round 3
// baseline (155.596 us; speedup 1.0000x reference)
//
#include <hip/hip_runtime.h>

// Reference: H=16, TP=8, C=257, T=S=128.  OUTPUT IS FLOAT32 (T,S,C,TP).
// ct_val[t,s,c,p] = (sum_p' d(sta[t,p'],pos[t,s,p']) - d(sta[t,p],pos[t,s,p])
//                    + d(cnc[t,c,p],pos[t,s,p])) / 8
// d(c1,c2,norm) = sign(c1>=0)*sign(c2>=0) * (1 - e/16) * norm,
//   e = frexp-exp of float(abs(c1)^abs(c2)+1) = 32 - clz(xor+1)
// so (1 - e/16) = (clz(xor+1) - 16) / 16   (exact integer form; verified:
// rounds 1 & 2 — bit-trick vs frexpf — produced identical outputs)

namespace {
constexpr int kTP = 8;
constexpr int kC  = 257;
constexpr int kT  = 128;
constexpr int kS  = 128;

typedef __attribute__((ext_vector_type(4))) int   int4v;
typedef __attribute__((ext_vector_type(4))) float float4v;

__device__ __forceinline__ float dist_f(int c1, int c2, float norm) {
    int x = (abs(c1) ^ abs(c2)) + 1;           // in [1, 2^16]
    float f = (float)(__clz(x) - 16);          // = 16 - e
    float v = f * norm * (1.0f / 16.0f);
    return ((c1 ^ c2) < 0) ? -v : v;           // sign(c1)*sign(c2)
}
} // namespace

__global__ __launch_bounds__(256) void critigraph_kernel(
    const int*   __restrict__ sta,   // (T,TP)
    const int*   __restrict__ pos,   // (T,S,TP)
    const int*   __restrict__ cnc,   // (T,C,TP)
    const float* __restrict__ eu,    // (T,S)
    float*       __restrict__ out)   // (T,S,C,TP) float32
{
    __shared__ float s_csp[kTP];
    __shared__ float s_np8[kTP];   // sign(pos)*norm/128  (= /16 dist scale /8 TP avg)
    __shared__ int   s_apos[kTP];  // |pos|

    const int bid = blockIdx.x;
    const int t = bid >> 7;        // S = 128
    const int s = bid & (kS - 1);
    const int tid = threadIdx.x;

    if (tid < kTP) {
        const int p  = tid;
        const int st = sta[t * kTP + p];
        const int po = pos[(t * kS + s) * kTP + p];
        const float norm = eu[t * kS + s];
        s_csp[p]  = dist_f(st, po, norm);
        s_apos[p] = abs(po);
        s_np8[p]  = (po >= 0 ? norm : -norm) * (1.0f / 128.0f);
    }
    __syncthreads();

    float csp[kTP], np8[kTP], base8[kTP];
    int   apos[kTP];
    float sum = 0.0f;
#pragma unroll
    for (int p = 0; p < kTP; ++p) {
        csp[p]  = s_csp[p];
        np8[p]  = s_np8[p];
        apos[p] = s_apos[p];
        sum += csp[p];
    }
#pragma unroll
    for (int p = 0; p < kTP; ++p)
        base8[p] = (sum - csp[p]) * 0.125f;   // (Σ - csp[p]) / 8

    const int* cbase = cnc + (size_t)t * kC * kTP;
    float* obase = out + (size_t)(t * kS + s) * (kC * kTP);

    // One candidate per lane; lane 0 also takes c = 256.
    for (int c = tid; c < kC; c += 256) {
        const int4v* cp = (const int4v*)(cbase + c * kTP); // 32B-aligned
        const int4v lo = cp[0];
        const int4v hi = cp[1];

        float4v r0, r1;
#pragma unroll
        for (int p = 0; p < kTP; ++p) {
            const int cn = (p < 4) ? lo[p] : hi[p - 4];
            const int x  = (abs(cn) ^ apos[p]) + 1;
            const float f = (float)(__clz(x) - 16);          // 16 - e
            // sign(cn) folded in by flipping the sign bit of np8[p]
            const float coeff = __int_as_float(
                __float_as_int(np8[p]) ^ (((unsigned)cn) & 0x80000000u));
            const float v = fmaf(f, coeff, base8[p]);
            if (p < 4) r0[p] = v; else r1[p - 4] = v;
        }

        float4v* op = (float4v*)(obase + c * kTP);  // 32B-aligned
        op[0] = r0;
        op[1] = r1;
    }
}

extern "C" void kernel_launch(void* const* d_in, const int* in_sizes, int n_in,
                              void* d_out, int out_size, void* d_ws, size_t ws_size,
                              hipStream_t stream) {
    const int*   sta = (const int*)d_in[0];
    const int*   pos = (const int*)d_in[1];
    const int*   cnc = (const int*)d_in[2];
    const float* eu  = (const float*)d_in[3];
    float*       out = (float*)d_out;

    const dim3 grid(kT * kS);  // one block per (t,s)
    const dim3 block(256);
    critigraph_kernel<<<grid, block, 0, stream>>>(sta, pos, cnc, eu, out);
}

// Round 4
// 147.817 us; speedup vs baseline: 1.0526x; 1.0526x over previous
//
#include <hip/hip_runtime.h>

// Reference: H=16, TP=8, C=257, T=S=128.  Output float32 (T,S,C,TP).
// ct_val[t,s,c,p] = (sum_p' d(sta[t,p'],pos[t,s,p']) - d(sta[t,p],pos[t,s,p])
//                    + d(cnc[t,c,p],pos[t,s,p])) / 8
// d(c1,c2,norm) = sign(c1>=0)*sign(c2>=0) * (1 - e/16) * norm
//   with e = frexp-exp(float(abs(c1)^abs(c2)+1)) = 32 - clz(xor+1)
//   => d = sign * norm * (clz(xor+1) - 16) / 16    (exact; verified r1==r2)
//
// Round 4: amortized structure. 2048 blocks = 128 t x 16 s-tiles (8 s each).
// Each thread owns one candidate c (abs/sign hoisted to registers), loops
// over 8 s. Per-s constants in a 1KB LDS table, read as uniform b128 rows.

namespace {
constexpr int kTP   = 8;
constexpr int kC    = 257;
constexpr int kT    = 128;
constexpr int kS    = 128;
constexpr int kSB   = 8;              // s per block
constexpr int kTile = kS / kSB;       // 16 s-tiles per t

typedef __attribute__((ext_vector_type(4))) int   int4v;
typedef __attribute__((ext_vector_type(4))) float float4v;
} // namespace

__global__ __launch_bounds__(256) void critigraph_kernel(
    const int*   __restrict__ sta,   // (T,TP)
    const int*   __restrict__ pos,   // (T,S,TP)
    const int*   __restrict__ cnc,   // (T,C,TP)
    const float* __restrict__ eu,    // (T,S)
    float*       __restrict__ out)   // (T,S,C,TP) f32
{
    __shared__ int   s_apos[kSB][kTP];   // |pos|
    __shared__ float s_np8[kSB][kTP];    // sign(pos)*norm/128
    __shared__ float s_csp[kSB][kTP];    // d(sta,pos)
    __shared__ float s_base8[kSB][kTP];  // (sum_p' csp - csp[p]) / 8

    const int t   = blockIdx.x >> 4;           // / kTile
    const int s0  = (blockIdx.x & (kTile - 1)) * kSB;
    const int tid = threadIdx.x;

    if (tid < kSB * kTP) {
        const int sl = tid >> 3;
        const int p  = tid & 7;
        const int s  = s0 + sl;
        const int st = sta[t * kTP + p];
        const int po = pos[(t * kS + s) * kTP + p];
        const float norm = eu[t * kS + s];
        const int x = (abs(st) ^ abs(po)) + 1;
        const float f = (float)(__clz(x) - 16);
        const float v = f * norm * (1.0f / 16.0f);
        s_csp[sl][p]  = ((st ^ po) < 0) ? -v : v;
        s_apos[sl][p] = abs(po);
        s_np8[sl][p]  = (po >= 0 ? norm : -norm) * (1.0f / 128.0f);
    }
    __syncthreads();
    if (tid < kSB * kTP) {
        const int sl = tid >> 3;
        const int p  = tid & 7;
        float sum = 0.0f;
#pragma unroll
        for (int q = 0; q < kTP; ++q) sum += s_csp[sl][q];
        s_base8[sl][p] = (sum - s_csp[sl][p]) * 0.125f;
    }
    __syncthreads();

    // ---- main: candidate c = tid (256 of the 257) ----
    {
        const int c = tid;
        const int* cb = cnc + ((size_t)t * kC + c) * kTP;   // 32B aligned
        const int4v lo = *(const int4v*)cb;
        const int4v hi = *(const int4v*)(cb + 4);
        int      acn[kTP];
        unsigned sg[kTP];
#pragma unroll
        for (int p = 0; p < kTP; ++p) {
            const int cn = (p < 4) ? lo[p] : hi[p - 4];
            acn[p] = abs(cn);
            sg[p]  = ((unsigned)cn) & 0x80000000u;
        }

        float* ob = out + ((size_t)(t * kS + s0) * kC + c) * kTP;
#pragma unroll
        for (int sl = 0; sl < kSB; ++sl) {
            // uniform-broadcast row loads (b128)
            const int4v   ap0 = *(const int4v*)&s_apos[sl][0];
            const int4v   ap1 = *(const int4v*)&s_apos[sl][4];
            const float4v np0 = *(const float4v*)&s_np8[sl][0];
            const float4v np1 = *(const float4v*)&s_np8[sl][4];
            const float4v b0  = *(const float4v*)&s_base8[sl][0];
            const float4v b1  = *(const float4v*)&s_base8[sl][4];

            float4v r0, r1;
#pragma unroll
            for (int p = 0; p < 4; ++p) {
                const int x = (acn[p] ^ ap0[p]) + 1;
                const float f = (float)(__clz(x) - 16);
                const float coeff = __int_as_float(__float_as_int(np0[p]) ^ sg[p]);
                r0[p] = fmaf(f, coeff, b0[p]);
            }
#pragma unroll
            for (int p = 0; p < 4; ++p) {
                const int x = (acn[p + 4] ^ ap1[p]) + 1;
                const float f = (float)(__clz(x) - 16);
                const float coeff = __int_as_float(__float_as_int(np1[p]) ^ sg[p + 4]);
                r1[p] = fmaf(f, coeff, b1[p]);
            }
            *(float4v*)ob       = r0;
            *(float4v*)(ob + 4) = r1;
            ob += (size_t)kC * kTP;   // next s row
        }
    }

    // ---- tail: candidate c = 256, lanes 0..7 (p = lane) ----
    if (tid < kTP) {
        const int p  = tid;
        const int cn = cnc[((size_t)t * kC + (kC - 1)) * kTP + p];
        const int a  = abs(cn);
        const unsigned sg = ((unsigned)cn) & 0x80000000u;
        float* ob = out + ((size_t)(t * kS + s0) * kC + (kC - 1)) * kTP + p;
#pragma unroll
        for (int sl = 0; sl < kSB; ++sl) {
            const int x = (a ^ s_apos[sl][p]) + 1;
            const float f = (float)(__clz(x) - 16);
            const float coeff = __int_as_float(__float_as_int(s_np8[sl][p]) ^ sg);
            ob[(size_t)sl * kC * kTP] = fmaf(f, coeff, s_base8[sl][p]);
        }
    }
}

extern "C" void kernel_launch(void* const* d_in, const int* in_sizes, int n_in,
                              void* d_out, int out_size, void* d_ws, size_t ws_size,
                              hipStream_t stream) {
    const int*   sta = (const int*)d_in[0];
    const int*   pos = (const int*)d_in[1];
    const int*   cnc = (const int*)d_in[2];
    const float* eu  = (const float*)d_in[3];
    float*       out = (float*)d_out;

    const dim3 grid(kT * kTile);   // 2048 blocks: (t, s-tile)
    const dim3 block(256);
    critigraph_kernel<<<grid, block, 0, stream>>>(sta, pos, cnc, eu, out);
}